// Round 19
// baseline (193.023 us; speedup 1.0000x reference)
//
#include <hip/hip_runtime.h>

typedef _Float16 f16;
typedef _Float16 f16x4 __attribute__((ext_vector_type(4)));
typedef _Float16 f16x8 __attribute__((ext_vector_type(8)));
typedef __fp16 h2 __attribute__((ext_vector_type(2)));
typedef float f32x4 __attribute__((ext_vector_type(4)));
typedef float f32x16 __attribute__((ext_vector_type(16)));

#define MFMA16(a, b, c) __builtin_amdgcn_mfma_f32_16x16x32_f16(a, b, c, 0, 0, 0)
#define MFMA32(a, b, c) __builtin_amdgcn_mfma_f32_32x32x16_f16(a, b, c, 0, 0, 0)

#if defined(__has_builtin)
#if __has_builtin(__builtin_amdgcn_fdot2)
#define HAS_FDOT2 1
#endif
#endif

typedef const __attribute__((address_space(1))) void gvoid;
typedef __attribute__((address_space(3))) void lvoid;
#define GLDS16(g, l) __builtin_amdgcn_global_load_lds((gvoid*)(g), (lvoid*)(l), 16, 0, 0)

// ---------------- kernel 0: convert weights to fp16 ----------------
__global__ __launch_bounds__(256) void wcvt_k(
    const float* __restrict__ tw, const float* __restrict__ pw,
    const float* __restrict__ gw, const float* __restrict__ ww,
    f16* __restrict__ Wall, f16* __restrict__ Wepi) {
  int i = blockIdx.x * 256 + threadIdx.x;
  if (i < 384 * 256) {
    int c = i >> 8, cp = i & 255;
    float v = (c < 128) ? tw[c * 256 + cp]
            : (c < 256) ? pw[(c - 128) * 256 + cp]
                        : gw[(c - 256) * 256 + cp];
    Wall[i] = (f16)v;
  }
  int j = i - 384 * 256;
  if (j >= 0 && j < 256 * 128) Wepi[j] = (f16)ww[j];
}

// ---------------- kernel 1: projection GEMM, reads x natively ----------------
// K and V written in SLOT-ORDERED tile layout (R13, verified).
__global__ __launch_bounds__(256) void proj_k(
    const float* __restrict__ x, const f16* __restrict__ Wall,
    const float* __restrict__ tb, const float* __restrict__ pb,
    const float* __restrict__ gb, f16* __restrict__ Q, f16* __restrict__ K,
    f16* __restrict__ Vt) {
  __shared__ f16 xs[64 * 264];
  __shared__ f16 vs[128 * 65];
  int b = blockIdx.x >> 6, nt = blockIdx.x & 63;
  int nbase = nt * 64;
  int tid = threadIdx.x;

  int nq = tid & 15, kq0 = tid >> 4;
#pragma unroll
  for (int p = 0; p < 4; ++p) {
    int kq = kq0 + 16 * p;
    float4 ld[4];
#pragma unroll
    for (int j = 0; j < 4; ++j)
      ld[j] = *(const float4*)(x + ((size_t)b * 256 + 4 * kq + j) * 4096 + nbase + 4 * nq);
#pragma unroll
    for (int e = 0; e < 4; ++e) {
      f16x4 wv = {(f16)((&ld[0].x)[e]), (f16)((&ld[1].x)[e]), (f16)((&ld[2].x)[e]),
                  (f16)((&ld[3].x)[e])};
      *(f16x4*)(&xs[(4 * nq + e) * 264 + 4 * kq]) = wv;
    }
  }
  __syncthreads();

  int w = tid >> 6, lane = tid & 63;
  int lr = lane & 15, lhi = lane >> 4;
  f16x8 a[8];
#pragma unroll
  for (int ks = 0; ks < 8; ++ks)
    a[ks] = *(const f16x8*)(&xs[(w * 16 + lr) * 264 + ks * 32 + lhi * 8]);
  f32x4 acc[24];
#pragma unroll
  for (int ct = 0; ct < 24; ++ct) {
    acc[ct] = {0.f, 0.f, 0.f, 0.f};
    const f16x8* wr = (const f16x8*)(Wall + (size_t)(ct * 16 + lr) * 256);
#pragma unroll
    for (int ks = 0; ks < 8; ++ks) acc[ct] = MFMA16(a[ks], wr[ks * 4 + lhi], acc[ct]);
  }
  int nloc = w * 16 + lhi * 4;
#pragma unroll
  for (int ct = 0; ct < 24; ++ct) {
    int c = ct * 16 + lr;
    float bias = (c < 128) ? tb[c] : (c < 256) ? pb[c - 128] : gb[c - 256];
#pragma unroll
    for (int r = 0; r < 4; ++r) {
      float v = acc[ct][r] + bias;
      int n = nbase + nloc + r;
      if (c < 128) {
        Q[((size_t)b * 4096 + n) * 128 + c] = (f16)v;
      } else if (c < 256) {
        int d = c - 128;
        int slot = ((d >> 4) << 6) + ((n & 31) << 1) + ((d >> 3) & 1);
        K[(size_t)b * 524288 + (size_t)(n >> 5) * 4096 + slot * 8 + (d & 7)] = (f16)v;
      } else {
        vs[(c - 256) * 65 + nloc + r] = (f16)v;
      }
    }
  }
  __syncthreads();
  f16* vo = Vt + (size_t)b * 524288;
  for (int rep = 0; rep < 32; ++rep) {
    int idx = rep * 256 + tid;
    int c = idx >> 6, j = idx & 63;  // c = channel d, j = local kv
    int n = nbase + j;
    int nl = j & 31;
    int p = (nl & 3) | ((nl & 4) << 1) | ((nl & 8) >> 1) | (nl & 16);
    int g = p >> 3, e = p & 7;
    int slot = ((c >> 5) << 7) + ((g >> 1) << 6) + ((c & 31) << 1) + (g & 1);
    vo[(size_t)(n >> 5) * 4096 + slot * 8 + e] = vs[c * 65 + j];
  }
}

// ---------------- kernel 2: flash attention, phase-shifted + chain-split -----
// R16 base (best, 105us attn) with serial-chain trims:
//  * QK^T split into TWO 4-deep MFMA chains (s2lo ks0-3, s2hi ks4-7, merged by
//    16 adds) -> exposed dependency latency halves.
//  * defer-max branch made WAVE-UNIFORM via __any (body semantics m=max(m,pm),
//    sc=exp(m_old-m_new): correct for lanes that didn't trigger).
//  * THR 8 -> 10 (P <= e^10 = 22K < f16 max) -> fewer rescale bodies.
__global__ __launch_bounds__(256, 2) void attn_k(const f16* __restrict__ Q,
                                                 const f16* __restrict__ K,
                                                 const f16* __restrict__ Vt,
                                                 f16* __restrict__ Yp,
                                                 float2* __restrict__ ml) {
  __shared__ f16 Ks[4][32 * 128];  // 8KB per buf, slot-ordered
  __shared__ f16 Vs[4][128 * 32];  // 8KB per buf, slot-ordered
  const float L = 1.44269504f;
  int swzid = ((blockIdx.x & 7) << 6) | ((int)blockIdx.x >> 3);
  int b = swzid >> 6, rem = swzid & 63;
  int qt = rem >> 1, s = rem & 1;
  int qbase = qt * 128;
  int tile0 = s * 64;  // 64 tiles of 32 kv per half
  int tid = threadIdx.x;
  int w = tid >> 6, lane = tid & 63;
  int col = lane & 31, hi = lane >> 5;

  const f16* Qr = Q + ((size_t)b * 4096 + qbase + w * 32 + col) * 128;
  f16x8 bq[8];
#pragma unroll
  for (int ks = 0; ks < 8; ++ks) bq[ks] = *(const f16x8*)(Qr + ks * 16 + hi * 8);

  f32x16 yacc[4];
#pragma unroll
  for (int dt = 0; dt < 4; ++dt)
#pragma unroll
    for (int r = 0; r < 16; ++r) yacc[dt][r] = 0.f;
  float lv[4] = {0.f, 0.f, 0.f, 0.f};
  float m = -1e30f, nmL = 1e30f;

  const char* KbB = (const char*)(K + (size_t)b * 524288);
  const char* VbB = (const char*)(Vt + (size_t)b * 524288);
  char* KsB = (char*)&Ks[0][0];
  char* VsB = (char*)&Vs[0][0];

  auto stage = [&](int t) {  // exactly 4 GLDS per wave, fixed order; buf = t&3
    size_t tb_ = (size_t)(tile0 + t) * 8192;
    const char* kb = KbB + tb_ + w * 2048 + lane * 16;
    const char* vb = VbB + tb_ + w * 2048 + lane * 16;
    char* kl = KsB + (t & 3) * 8192 + w * 2048;
    char* vl = VsB + (t & 3) * 8192 + w * 2048;
#pragma unroll
    for (int c = 0; c < 2; ++c) {
      GLDS16(kb + c * 1024, kl + c * 1024);
      GLDS16(vb + c * 1024, vl + c * 1024);
    }
  };

  int lanebase = col * 32 + hi * 16;

  auto qkt = [&](int p, f32x16& sN) {
    const char* kcur = KsB + (p & 3) * 8192 + lanebase;
    f32x16 slo, shi;
#pragma unroll
    for (int r = 0; r < 16; ++r) {
      slo[r] = 0.f;
      shi[r] = 0.f;
    }
    __builtin_amdgcn_s_setprio(1);
#pragma unroll
    for (int ks = 0; ks < 4; ++ks) {
      f16x8 ak0 = *(const f16x8*)(kcur + ks * 1024);
      slo = MFMA32(ak0, bq[ks], slo);
      f16x8 ak1 = *(const f16x8*)(kcur + (ks + 4) * 1024);
      shi = MFMA32(ak1, bq[ks + 4], shi);
    }
    __builtin_amdgcn_s_setprio(0);
#pragma unroll
    for (int r = 0; r < 16; ++r) sN[r] = slo[r] + shi[r];
  };

  auto smpv = [&](int t, f32x16& sO) {
    float a0 = fmaxf(fmaxf(sO[0], sO[1]), sO[2]);
    float a1 = fmaxf(fmaxf(sO[3], sO[4]), sO[5]);
    float a2 = fmaxf(fmaxf(sO[6], sO[7]), sO[8]);
    float a3 = fmaxf(fmaxf(sO[9], sO[10]), sO[11]);
    float a4 = fmaxf(fmaxf(sO[12], sO[13]), sO[14]);
    float pm = fmaxf(fmaxf(fmaxf(a0, a1), fmaxf(a2, a3)), fmaxf(a4, sO[15]));
    pm = fmaxf(pm, __shfl_xor(pm, 32));
    if (__any(pm > m + 10.f)) {  // T13 defer-max, wave-uniform branch
      float mn = fmaxf(m, pm);
      float sc = __expf(m - mn);
      m = mn;
      nmL = -m * L;
#pragma unroll
      for (int i = 0; i < 4; ++i) lv[i] *= sc;
#pragma unroll
      for (int dt = 0; dt < 4; ++dt)
#pragma unroll
        for (int r = 0; r < 16; ++r) yacc[dt][r] *= sc;
    }
#pragma unroll
    for (int r = 0; r < 16; ++r) sO[r] = exp2f(fmaf(sO[r], L, nmL));

    f16x8 pfrA, pfrB;
#pragma unroll
    for (int c = 0; c < 8; ++c) {
      pfrA[c] = (f16)sO[c];
      pfrB[c] = (f16)sO[8 + c];
    }
#if defined(HAS_FDOT2)
    {
      h2 one2 = {1.0f, 1.0f};
      const h2* pa = (const h2*)&pfrA;
      const h2* pb2 = (const h2*)&pfrB;
#pragma unroll
      for (int j = 0; j < 4; ++j) {
        lv[j] = __builtin_amdgcn_fdot2(pa[j], one2, lv[j], false);
        lv[j] = __builtin_amdgcn_fdot2(pb2[j], one2, lv[j], false);
      }
    }
#else
#pragma unroll
    for (int j = 0; j < 4; ++j)
      lv[j] += (float)pfrA[2 * j] + (float)pfrA[2 * j + 1] + (float)pfrB[2 * j] +
               (float)pfrB[2 * j + 1];
#endif
    __builtin_amdgcn_s_setprio(1);
    const char* vcur = VsB + (t & 3) * 8192 + lanebase;
#pragma unroll
    for (int dt = 0; dt < 4; ++dt) {
      f16x8 av0 = *(const f16x8*)(vcur + dt * 2048);
      yacc[dt] = MFMA32(av0, pfrA, yacc[dt]);
      f16x8 av1 = *(const f16x8*)(vcur + dt * 2048 + 1024);
      yacc[dt] = MFMA32(av1, pfrB, yacc[dt]);
    }
    __builtin_amdgcn_s_setprio(0);
  };

#define PH_WAIT4 asm volatile("s_waitcnt vmcnt(4)" ::: "memory")
#define PH_WAIT0 asm volatile("s_waitcnt vmcnt(0)" ::: "memory")

  f32x16 sA, sB;
  stage(0);
  stage(1);
  // phase 0
  PH_WAIT4;
  __builtin_amdgcn_s_barrier();
  stage(2);
  qkt(0, sA);
  // phase 1
  PH_WAIT4;
  __builtin_amdgcn_s_barrier();
  stage(3);
  qkt(1, sB);
  smpv(0, sA);
  // phases 2..61 (stage p+2 = 4..63)
  for (int p = 2; p < 62; p += 2) {
    PH_WAIT4;
    __builtin_amdgcn_s_barrier();
    stage(p + 2);
    qkt(p, sA);
    smpv(p - 1, sB);
    PH_WAIT4;
    __builtin_amdgcn_s_barrier();
    stage(p + 3);
    qkt(p + 1, sB);
    smpv(p, sA);
  }
  // phase 62
  PH_WAIT4;
  __builtin_amdgcn_s_barrier();
  qkt(62, sA);
  smpv(61, sB);
  // phase 63
  PH_WAIT0;
  __builtin_amdgcn_s_barrier();
  qkt(63, sB);
  smpv(62, sA);
  // epilogue phase
  smpv(63, sB);

  float l = (lv[0] + lv[1]) + (lv[2] + lv[3]);
  l += __shfl_xor(l, 32);

  int rowG = b * 4096 + qbase + w * 32 + col;
  f16* yo = Yp + ((size_t)s * 32768 + rowG) * 128;
  float inv = 1.0f / l;
#pragma unroll
  for (int dt = 0; dt < 4; ++dt)
#pragma unroll
    for (int a = 0; a < 4; ++a) {
      f16x4 ov = {(f16)(yacc[dt][4 * a] * inv), (f16)(yacc[dt][4 * a + 1] * inv),
                  (f16)(yacc[dt][4 * a + 2] * inv), (f16)(yacc[dt][4 * a + 3] * inv)};
      *(f16x4*)(yo + dt * 32 + a * 8 + hi * 4) = ov;
    }
  if (hi == 0) ml[s * 32768 + rowG] = make_float2(m, l);
}

// ---------------- kernel 3: 2-way combine + epilogue GEMM + bias + residual ----
__global__ __launch_bounds__(256) void epi_k(const f16* __restrict__ Yp,
                                             const float2* __restrict__ ml,
                                             const f16* __restrict__ Wepi,
                                             const float* __restrict__ Wb,
                                             const float* __restrict__ x,
                                             float* __restrict__ out) {
  int b = blockIdx.x >> 6, nt = blockIdx.x & 63;
  int nbase = nt * 64;
  int w = threadIdx.x >> 6, lane = threadIdx.x & 63;
  int lr = lane & 15, lhi = lane >> 4;
  const f16* yb1 = Yp + (size_t)32768 * 128;
  f16x8 by[4][4];
#pragma unroll
  for (int n4 = 0; n4 < 4; ++n4) {
    int row = b * 4096 + nbase + n4 * 16 + lr;
    float2 m0 = ml[row], m1 = ml[32768 + row];
    float mm = fmaxf(m0.x, m1.x);
    float w0 = m0.y * __expf(m0.x - mm), w1 = m1.y * __expf(m1.x - mm);
    float inv = 1.f / (w0 + w1);
    w0 *= inv;
    w1 *= inv;
    size_t rb = (size_t)row * 128;
#pragma unroll
    for (int ks = 0; ks < 4; ++ks) {
      int eo = ks * 32 + lhi * 8;
      f16x8 a0 = *(const f16x8*)(Yp + rb + eo);
      f16x8 a1 = *(const f16x8*)(yb1 + rb + eo);
      f16x8 o;
#pragma unroll
      for (int e = 0; e < 8; ++e) o[e] = (f16)(w0 * (float)a0[e] + w1 * (float)a1[e]);
      by[n4][ks] = o;
    }
  }
#pragma unroll
  for (int ot = 0; ot < 4; ++ot) {
    int o0 = w * 64 + ot * 16;
    const f16x8* wr = (const f16x8*)(Wepi + (size_t)(o0 + lr) * 128);
    f16x8 a[4];
#pragma unroll
    for (int ks = 0; ks < 4; ++ks) a[ks] = wr[ks * 4 + lhi];
#pragma unroll
    for (int n4 = 0; n4 < 4; ++n4) {
      f32x4 acc = {0.f, 0.f, 0.f, 0.f};
#pragma unroll
      for (int ks = 0; ks < 4; ++ks) acc = MFMA16(a[ks], by[n4][ks], acc);
#pragma unroll
      for (int r = 0; r < 4; ++r) {
        int o = o0 + lhi * 4 + r;
        int n = nbase + n4 * 16 + lr;
        size_t idx = ((size_t)b * 256 + o) * 4096 + n;
        out[idx] = x[idx] + Wb[o] + acc[r];
      }
    }
  }
}

extern "C" void kernel_launch(void* const* d_in, const int* in_sizes, int n_in,
                              void* d_out, int out_size, void* d_ws, size_t ws_size,
                              hipStream_t stream) {
  const float* x       = (const float*)d_in[0];
  const float* g_w     = (const float*)d_in[1];
  const float* g_b     = (const float*)d_in[2];
  const float* theta_w = (const float*)d_in[3];
  const float* theta_b = (const float*)d_in[4];
  const float* phi_w   = (const float*)d_in[5];
  const float* phi_b   = (const float*)d_in[6];
  const float* W_w     = (const float*)d_in[7];
  const float* W_b     = (const float*)d_in[8];
  float* out = (float*)d_out;

  f16* Q    = (f16*)d_ws;                       // [8,4096,128] 8MB
  f16* Kk   = Q + (size_t)8 * 4096 * 128;       // 8MB (slot-ordered tiles)
  f16* Vt   = Kk + (size_t)8 * 4096 * 128;      // 8MB (slot-ordered tiles)
  f16* Wall = Vt + (size_t)8 * 4096 * 128;      // [384,256]
  f16* Wepi = Wall + 384 * 256;                 // [256,128]
  float2* ml = (float2*)(Wepi + 256 * 128);     // [2][32768] 0.5MB
  f16* Yp   = (f16*)(ml + 2 * 32768);           // [2][32768][128] 16MB (~41MB total)

  wcvt_k<<<512, 256, 0, stream>>>(theta_w, phi_w, g_w, W_w, Wall, Wepi);
  proj_k<<<512, 256, 0, stream>>>(x, Wall, theta_b, phi_b, g_b, Q, Kk, Vt);
  attn_k<<<512, 256, 0, stream>>>(Q, Kk, Vt, Yp, ml);
  epi_k<<<512, 256, 0, stream>>>(Yp, ml, Wepi, W_b, x, out);
}

// Round 20
// 184.266 us; speedup vs baseline: 1.0475x; 1.0475x over previous
//
#include <hip/hip_runtime.h>

typedef _Float16 f16;
typedef _Float16 f16x4 __attribute__((ext_vector_type(4)));
typedef _Float16 f16x8 __attribute__((ext_vector_type(8)));
typedef __fp16 h2 __attribute__((ext_vector_type(2)));
typedef float f32x4 __attribute__((ext_vector_type(4)));
typedef float f32x16 __attribute__((ext_vector_type(16)));

#define MFMA16(a, b, c) __builtin_amdgcn_mfma_f32_16x16x32_f16(a, b, c, 0, 0, 0)
#define MFMA32(a, b, c) __builtin_amdgcn_mfma_f32_32x32x16_f16(a, b, c, 0, 0, 0)

#if defined(__has_builtin)
#if __has_builtin(__builtin_amdgcn_fdot2)
#define HAS_FDOT2 1
#endif
#endif

typedef const __attribute__((address_space(1))) void gvoid;
typedef __attribute__((address_space(3))) void lvoid;
#define GLDS16(g, l) __builtin_amdgcn_global_load_lds((gvoid*)(g), (lvoid*)(l), 16, 0, 0)

// ---------------- kernel 0: convert weights to fp16 ----------------
__global__ __launch_bounds__(256) void wcvt_k(
    const float* __restrict__ tw, const float* __restrict__ pw,
    const float* __restrict__ gw, const float* __restrict__ ww,
    f16* __restrict__ Wall, f16* __restrict__ Wepi) {
  int i = blockIdx.x * 256 + threadIdx.x;
  if (i < 384 * 256) {
    int c = i >> 8, cp = i & 255;
    float v = (c < 128) ? tw[c * 256 + cp]
            : (c < 256) ? pw[(c - 128) * 256 + cp]
                        : gw[(c - 256) * 256 + cp];
    Wall[i] = (f16)v;
  }
  int j = i - 384 * 256;
  if (j >= 0 && j < 256 * 128) Wepi[j] = (f16)ww[j];
}

// ---------------- kernel 1: projection GEMM, reads x natively ----------------
// K and V written in SLOT-ORDERED tile layout (R13, verified).
__global__ __launch_bounds__(256) void proj_k(
    const float* __restrict__ x, const f16* __restrict__ Wall,
    const float* __restrict__ tb, const float* __restrict__ pb,
    const float* __restrict__ gb, f16* __restrict__ Q, f16* __restrict__ K,
    f16* __restrict__ Vt) {
  __shared__ f16 xs[64 * 264];
  __shared__ f16 vs[128 * 65];
  int b = blockIdx.x >> 6, nt = blockIdx.x & 63;
  int nbase = nt * 64;
  int tid = threadIdx.x;

  int nq = tid & 15, kq0 = tid >> 4;
#pragma unroll
  for (int p = 0; p < 4; ++p) {
    int kq = kq0 + 16 * p;
    float4 ld[4];
#pragma unroll
    for (int j = 0; j < 4; ++j)
      ld[j] = *(const float4*)(x + ((size_t)b * 256 + 4 * kq + j) * 4096 + nbase + 4 * nq);
#pragma unroll
    for (int e = 0; e < 4; ++e) {
      f16x4 wv = {(f16)((&ld[0].x)[e]), (f16)((&ld[1].x)[e]), (f16)((&ld[2].x)[e]),
                  (f16)((&ld[3].x)[e])};
      *(f16x4*)(&xs[(4 * nq + e) * 264 + 4 * kq]) = wv;
    }
  }
  __syncthreads();

  int w = tid >> 6, lane = tid & 63;
  int lr = lane & 15, lhi = lane >> 4;
  f16x8 a[8];
#pragma unroll
  for (int ks = 0; ks < 8; ++ks)
    a[ks] = *(const f16x8*)(&xs[(w * 16 + lr) * 264 + ks * 32 + lhi * 8]);
  f32x4 acc[24];
#pragma unroll
  for (int ct = 0; ct < 24; ++ct) {
    acc[ct] = {0.f, 0.f, 0.f, 0.f};
    const f16x8* wr = (const f16x8*)(Wall + (size_t)(ct * 16 + lr) * 256);
#pragma unroll
    for (int ks = 0; ks < 8; ++ks) acc[ct] = MFMA16(a[ks], wr[ks * 4 + lhi], acc[ct]);
  }
  int nloc = w * 16 + lhi * 4;
#pragma unroll
  for (int ct = 0; ct < 24; ++ct) {
    int c = ct * 16 + lr;
    float bias = (c < 128) ? tb[c] : (c < 256) ? pb[c - 128] : gb[c - 256];
#pragma unroll
    for (int r = 0; r < 4; ++r) {
      float v = acc[ct][r] + bias;
      int n = nbase + nloc + r;
      if (c < 128) {
        Q[((size_t)b * 4096 + n) * 128 + c] = (f16)v;
      } else if (c < 256) {
        int d = c - 128;
        int slot = ((d >> 4) << 6) + ((n & 31) << 1) + ((d >> 3) & 1);
        K[(size_t)b * 524288 + (size_t)(n >> 5) * 4096 + slot * 8 + (d & 7)] = (f16)v;
      } else {
        vs[(c - 256) * 65 + nloc + r] = (f16)v;
      }
    }
  }
  __syncthreads();
  f16* vo = Vt + (size_t)b * 524288;
  for (int rep = 0; rep < 32; ++rep) {
    int idx = rep * 256 + tid;
    int c = idx >> 6, j = idx & 63;  // c = channel d, j = local kv
    int n = nbase + j;
    int nl = j & 31;
    int p = (nl & 3) | ((nl & 4) << 1) | ((nl & 8) >> 1) | (nl & 16);
    int g = p >> 3, e = p & 7;
    int slot = ((c >> 5) << 7) + ((g >> 1) << 6) + ((c & 31) << 1) + (g & 1);
    vo[(size_t)(n >> 5) * 4096 + slot * 8 + e] = vs[c * 65 + j];
  }
}

// ---------------- kernel 2: flash attention, phase-shifted pipeline ----------
// Best measured config (R16, attn 105us): per phase do qkt(p) FIRST, then
// softmax+PV of tile p-1 (S-pingpong sA/sB): softmax consumes phase-old MFMA
// results and its VALU sits adjacent to qkt's MFMA cluster -> compiler
// interleaves (separate pipes). 4-buffer LDS rotation (64KB), vmcnt(4) counted.
__global__ __launch_bounds__(256, 2) void attn_k(const f16* __restrict__ Q,
                                                 const f16* __restrict__ K,
                                                 const f16* __restrict__ Vt,
                                                 f16* __restrict__ Yp,
                                                 float2* __restrict__ ml) {
  __shared__ f16 Ks[4][32 * 128];  // 8KB per buf, slot-ordered
  __shared__ f16 Vs[4][128 * 32];  // 8KB per buf, slot-ordered
  const float L = 1.44269504f;
  int swzid = ((blockIdx.x & 7) << 6) | ((int)blockIdx.x >> 3);
  int b = swzid >> 6, rem = swzid & 63;
  int qt = rem >> 1, s = rem & 1;
  int qbase = qt * 128;
  int tile0 = s * 64;  // 64 tiles of 32 kv per half
  int tid = threadIdx.x;
  int w = tid >> 6, lane = tid & 63;
  int col = lane & 31, hi = lane >> 5;

  const f16* Qr = Q + ((size_t)b * 4096 + qbase + w * 32 + col) * 128;
  f16x8 bq[8];
#pragma unroll
  for (int ks = 0; ks < 8; ++ks) bq[ks] = *(const f16x8*)(Qr + ks * 16 + hi * 8);

  f32x16 yacc[4];
#pragma unroll
  for (int dt = 0; dt < 4; ++dt)
#pragma unroll
    for (int r = 0; r < 16; ++r) yacc[dt][r] = 0.f;
  float lv[4] = {0.f, 0.f, 0.f, 0.f};
  float m = -1e30f, nmL = 1e30f;

  const char* KbB = (const char*)(K + (size_t)b * 524288);
  const char* VbB = (const char*)(Vt + (size_t)b * 524288);
  char* KsB = (char*)&Ks[0][0];
  char* VsB = (char*)&Vs[0][0];

  auto stage = [&](int t) {  // exactly 4 GLDS per wave, fixed order; buf = t&3
    size_t tb_ = (size_t)(tile0 + t) * 8192;
    const char* kb = KbB + tb_ + w * 2048 + lane * 16;
    const char* vb = VbB + tb_ + w * 2048 + lane * 16;
    char* kl = KsB + (t & 3) * 8192 + w * 2048;
    char* vl = VsB + (t & 3) * 8192 + w * 2048;
#pragma unroll
    for (int c = 0; c < 2; ++c) {
      GLDS16(kb + c * 1024, kl + c * 1024);
      GLDS16(vb + c * 1024, vl + c * 1024);
    }
  };

  int lanebase = col * 32 + hi * 16;

  auto qkt = [&](int p, f32x16& sN) {
    const char* kcur = KsB + (p & 3) * 8192 + lanebase;
#pragma unroll
    for (int r = 0; r < 16; ++r) sN[r] = 0.f;
    __builtin_amdgcn_s_setprio(1);
#pragma unroll
    for (int ks = 0; ks < 8; ++ks) {
      f16x8 ak = *(const f16x8*)(kcur + ks * 1024);
      sN = MFMA32(ak, bq[ks], sN);
    }
    __builtin_amdgcn_s_setprio(0);
  };

  auto smpv = [&](int t, f32x16& sO) {
    float a0 = fmaxf(fmaxf(sO[0], sO[1]), sO[2]);
    float a1 = fmaxf(fmaxf(sO[3], sO[4]), sO[5]);
    float a2 = fmaxf(fmaxf(sO[6], sO[7]), sO[8]);
    float a3 = fmaxf(fmaxf(sO[9], sO[10]), sO[11]);
    float a4 = fmaxf(fmaxf(sO[12], sO[13]), sO[14]);
    float pm = fmaxf(fmaxf(fmaxf(a0, a1), fmaxf(a2, a3)), fmaxf(a4, sO[15]));
    pm = fmaxf(pm, __shfl_xor(pm, 32));
    if (pm > m + 8.f) {  // T13 defer-max
      float sc = __expf(m - pm);
      m = pm;
      nmL = -m * L;
#pragma unroll
      for (int i = 0; i < 4; ++i) lv[i] *= sc;
#pragma unroll
      for (int dt = 0; dt < 4; ++dt)
#pragma unroll
        for (int r = 0; r < 16; ++r) yacc[dt][r] *= sc;
    }
#pragma unroll
    for (int r = 0; r < 16; ++r) sO[r] = exp2f(fmaf(sO[r], L, nmL));

    f16x8 pfrA, pfrB;
#pragma unroll
    for (int c = 0; c < 8; ++c) {
      pfrA[c] = (f16)sO[c];
      pfrB[c] = (f16)sO[8 + c];
    }
#if defined(HAS_FDOT2)
    {
      h2 one2 = {1.0f, 1.0f};
      const h2* pa = (const h2*)&pfrA;
      const h2* pb2 = (const h2*)&pfrB;
#pragma unroll
      for (int j = 0; j < 4; ++j) {
        lv[j] = __builtin_amdgcn_fdot2(pa[j], one2, lv[j], false);
        lv[j] = __builtin_amdgcn_fdot2(pb2[j], one2, lv[j], false);
      }
    }
#else
#pragma unroll
    for (int j = 0; j < 4; ++j)
      lv[j] += (float)pfrA[2 * j] + (float)pfrA[2 * j + 1] + (float)pfrB[2 * j] +
               (float)pfrB[2 * j + 1];
#endif
    __builtin_amdgcn_s_setprio(1);
    const char* vcur = VsB + (t & 3) * 8192 + lanebase;
#pragma unroll
    for (int dt = 0; dt < 4; ++dt) {
      f16x8 av0 = *(const f16x8*)(vcur + dt * 2048);
      yacc[dt] = MFMA32(av0, pfrA, yacc[dt]);
      f16x8 av1 = *(const f16x8*)(vcur + dt * 2048 + 1024);
      yacc[dt] = MFMA32(av1, pfrB, yacc[dt]);
    }
    __builtin_amdgcn_s_setprio(0);
  };

#define PH_WAIT4 asm volatile("s_waitcnt vmcnt(4)" ::: "memory")
#define PH_WAIT0 asm volatile("s_waitcnt vmcnt(0)" ::: "memory")

  f32x16 sA, sB;
  stage(0);
  stage(1);
  // phase 0
  PH_WAIT4;
  __builtin_amdgcn_s_barrier();
  stage(2);
  qkt(0, sA);
  // phase 1
  PH_WAIT4;
  __builtin_amdgcn_s_barrier();
  stage(3);
  qkt(1, sB);
  smpv(0, sA);
  // phases 2..61 (stage p+2 = 4..63)
  for (int p = 2; p < 62; p += 2) {
    PH_WAIT4;
    __builtin_amdgcn_s_barrier();
    stage(p + 2);
    qkt(p, sA);
    smpv(p - 1, sB);
    PH_WAIT4;
    __builtin_amdgcn_s_barrier();
    stage(p + 3);
    qkt(p + 1, sB);
    smpv(p, sA);
  }
  // phase 62
  PH_WAIT4;
  __builtin_amdgcn_s_barrier();
  qkt(62, sA);
  smpv(61, sB);
  // phase 63
  PH_WAIT0;
  __builtin_amdgcn_s_barrier();
  qkt(63, sB);
  smpv(62, sA);
  // epilogue phase
  smpv(63, sB);

  float l = (lv[0] + lv[1]) + (lv[2] + lv[3]);
  l += __shfl_xor(l, 32);

  int rowG = b * 4096 + qbase + w * 32 + col;
  f16* yo = Yp + ((size_t)s * 32768 + rowG) * 128;
  float inv = 1.0f / l;
#pragma unroll
  for (int dt = 0; dt < 4; ++dt)
#pragma unroll
    for (int a = 0; a < 4; ++a) {
      f16x4 ov = {(f16)(yacc[dt][4 * a] * inv), (f16)(yacc[dt][4 * a + 1] * inv),
                  (f16)(yacc[dt][4 * a + 2] * inv), (f16)(yacc[dt][4 * a + 3] * inv)};
      *(f16x4*)(yo + dt * 32 + a * 8 + hi * 4) = ov;
    }
  if (hi == 0) ml[s * 32768 + rowG] = make_float2(m, l);
}

// ---------------- kernel 3: 2-way combine + epilogue GEMM + bias + residual ----
__global__ __launch_bounds__(256) void epi_k(const f16* __restrict__ Yp,
                                             const float2* __restrict__ ml,
                                             const f16* __restrict__ Wepi,
                                             const float* __restrict__ Wb,
                                             const float* __restrict__ x,
                                             float* __restrict__ out) {
  int b = blockIdx.x >> 6, nt = blockIdx.x & 63;
  int nbase = nt * 64;
  int w = threadIdx.x >> 6, lane = threadIdx.x & 63;
  int lr = lane & 15, lhi = lane >> 4;
  const f16* yb1 = Yp + (size_t)32768 * 128;
  f16x8 by[4][4];
#pragma unroll
  for (int n4 = 0; n4 < 4; ++n4) {
    int row = b * 4096 + nbase + n4 * 16 + lr;
    float2 m0 = ml[row], m1 = ml[32768 + row];
    float mm = fmaxf(m0.x, m1.x);
    float w0 = m0.y * __expf(m0.x - mm), w1 = m1.y * __expf(m1.x - mm);
    float inv = 1.f / (w0 + w1);
    w0 *= inv;
    w1 *= inv;
    size_t rb = (size_t)row * 128;
#pragma unroll
    for (int ks = 0; ks < 4; ++ks) {
      int eo = ks * 32 + lhi * 8;
      f16x8 a0 = *(const f16x8*)(Yp + rb + eo);
      f16x8 a1 = *(const f16x8*)(yb1 + rb + eo);
      f16x8 o;
#pragma unroll
      for (int e = 0; e < 8; ++e) o[e] = (f16)(w0 * (float)a0[e] + w1 * (float)a1[e]);
      by[n4][ks] = o;
    }
  }
#pragma unroll
  for (int ot = 0; ot < 4; ++ot) {
    int o0 = w * 64 + ot * 16;
    const f16x8* wr = (const f16x8*)(Wepi + (size_t)(o0 + lr) * 128);
    f16x8 a[4];
#pragma unroll
    for (int ks = 0; ks < 4; ++ks) a[ks] = wr[ks * 4 + lhi];
#pragma unroll
    for (int n4 = 0; n4 < 4; ++n4) {
      f32x4 acc = {0.f, 0.f, 0.f, 0.f};
#pragma unroll
      for (int ks = 0; ks < 4; ++ks) acc = MFMA16(a[ks], by[n4][ks], acc);
#pragma unroll
      for (int r = 0; r < 4; ++r) {
        int o = o0 + lhi * 4 + r;
        int n = nbase + n4 * 16 + lr;
        size_t idx = ((size_t)b * 256 + o) * 4096 + n;
        out[idx] = x[idx] + Wb[o] + acc[r];
      }
    }
  }
}

extern "C" void kernel_launch(void* const* d_in, const int* in_sizes, int n_in,
                              void* d_out, int out_size, void* d_ws, size_t ws_size,
                              hipStream_t stream) {
  const float* x       = (const float*)d_in[0];
  const float* g_w     = (const float*)d_in[1];
  const float* g_b     = (const float*)d_in[2];
  const float* theta_w = (const float*)d_in[3];
  const float* theta_b = (const float*)d_in[4];
  const float* phi_w   = (const float*)d_in[5];
  const float* phi_b   = (const float*)d_in[6];
  const float* W_w     = (const float*)d_in[7];
  const float* W_b     = (const float*)d_in[8];
  float* out = (float*)d_out;

  f16* Q    = (f16*)d_ws;                       // [8,4096,128] 8MB
  f16* Kk   = Q + (size_t)8 * 4096 * 128;       // 8MB (slot-ordered tiles)
  f16* Vt   = Kk + (size_t)8 * 4096 * 128;      // 8MB (slot-ordered tiles)
  f16* Wall = Vt + (size_t)8 * 4096 * 128;      // [384,256]
  f16* Wepi = Wall + 384 * 256;                 // [256,128]
  float2* ml = (float2*)(Wepi + 256 * 128);     // [2][32768] 0.5MB
  f16* Yp   = (f16*)(ml + 2 * 32768);           // [2][32768][128] 16MB (~41MB total)

  wcvt_k<<<512, 256, 0, stream>>>(theta_w, phi_w, g_w, W_w, Wall, Wepi);
  proj_k<<<512, 256, 0, stream>>>(x, Wall, theta_b, phi_b, g_b, Q, Kk, Vt);
  attn_k<<<512, 256, 0, stream>>>(Q, Kk, Vt, Yp, ml);
  epi_k<<<512, 256, 0, stream>>>(Yp, ml, Wepi, W_b, x, out);
}